// Round 1
// baseline (84427.985 us; speedup 1.0000x reference)
//
#include <hip/hip_runtime.h>
#include <hip/hip_fp16.h>

// ============================================================================
// Bidirectional 2-layer GRU (T=32768, C=64, H=256) + Gaussian heads (K=10).
//
// Decomposition:
//   1. cvt_x:      x f32 -> f16
//   2. gemm_f16:   i_all = x @ w_ih^T   (bias folded into recurrence), f16 MFMA
//   3. recur:      persistent 1-block-per-direction GRU scan. Weights w_hh live
//                  in VGPRs as 16x16x32 f16 MFMA A-fragments (192 VGPR/thread).
//                  h is broadcast via B-fragments (MFMA does the lane
//                  broadcast in HW). Gates in f32, recurrent carry in f32 reg.
//   4. gemm_f16:   layer-1 i_all from concat(out_f, out_b)
//   5. recur:      layer-1 scan
//   6. head:       [mu | softplus heads] as a skinny (N=32-padded) f16 MFMA GEMM
//
// Workspace (f16 storage, ~164 MB):
//   xh      @ 0        : T*64*2   =   4 MB
//   iall_f  @ 4MB      : T*768*2  =  48 MB
//   iall_b  @ 52MB     : T*768*2  =  48 MB   (both i_all buffers reused by layer 1)
//   out0    @ 100MB    : T*512*2  =  32 MB
//   out1    @ 132MB    : T*512*2  =  32 MB
// ============================================================================

typedef _Float16 f16x8 __attribute__((ext_vector_type(8)));
typedef float    f32x4 __attribute__((ext_vector_type(4)));

#define T_LEN 32768
#define HDIM  256

// ---------------------------------------------------------------------------
// x (f32) -> f16
// ---------------------------------------------------------------------------
__global__ void cvt_x_kernel(const float* __restrict__ x, __half* __restrict__ xh) {
    int i = (blockIdx.x * 256 + threadIdx.x) * 8;
    f32x4 a = *reinterpret_cast<const f32x4*>(x + i);
    f32x4 b = *reinterpret_cast<const f32x4*>(x + i + 4);
    f16x8 v;
#pragma unroll
    for (int j = 0; j < 4; ++j) { v[j] = (_Float16)a[j]; v[4 + j] = (_Float16)b[j]; }
    *reinterpret_cast<f16x8*>(xh + i) = v;
}

// ---------------------------------------------------------------------------
// C(M x 768) = A(M x K, f16) @ B(768 x K, f32)^T, C stored f16.  BM=BN=128, BK=32.
// 256 threads (4 waves), each wave a 64x64 quadrant of 16x16x32 MFMA tiles.
// blockIdx.z selects direction (two weight/output sets, shared A).
// ---------------------------------------------------------------------------
__global__ __launch_bounds__(256, 1)
void gemm_f16_kernel(const __half* __restrict__ A,
                     const float* __restrict__ B0, const float* __restrict__ B1,
                     __half* __restrict__ C0, __half* __restrict__ C1, int K) {
    const float* B = blockIdx.z ? B1 : B0;
    __half*      C = blockIdx.z ? C1 : C0;
    const int m0 = blockIdx.x * 128, n0 = blockIdx.y * 128;
    const int tid = threadIdx.x, lane = tid & 63, wv = tid >> 6;
    const int wm = (wv >> 1) * 64, wn = (wv & 1) * 64;
    const int qq = lane >> 4, r16 = lane & 15;

    // +8 f16 pad -> row stride 80B, worst-case 2-way LDS conflict (free)
    __shared__ __align__(16) _Float16 As[128][40];
    __shared__ __align__(16) _Float16 Bs[128][40];

    f32x4 acc[4][4];
#pragma unroll
    for (int i = 0; i < 4; ++i)
#pragma unroll
        for (int j = 0; j < 4; ++j) acc[i][j] = (f32x4){0.f, 0.f, 0.f, 0.f};

    const int r = tid >> 1, seg = tid & 1;
    for (int k0 = 0; k0 < K; k0 += 32) {
        // stage A (already f16): 2 x 16B loads per thread
        const f16x8* ap = reinterpret_cast<const f16x8*>(A + (size_t)(m0 + r) * K + k0 + 16 * seg);
        f16x8 a0 = ap[0], a1 = ap[1];
        // stage B (f32 -> f16): 4 x 16B loads per thread
        const f32x4* bp = reinterpret_cast<const f32x4*>(B + (size_t)(n0 + r) * K + k0 + 16 * seg);
        f32x4 b0v = bp[0], b1v = bp[1], b2v = bp[2], b3v = bp[3];
        f16x8 bh0, bh1;
#pragma unroll
        for (int j = 0; j < 4; ++j) {
            bh0[j] = (_Float16)b0v[j]; bh0[4 + j] = (_Float16)b1v[j];
            bh1[j] = (_Float16)b2v[j]; bh1[4 + j] = (_Float16)b3v[j];
        }
        *reinterpret_cast<f16x8*>(&As[r][16 * seg])     = a0;
        *reinterpret_cast<f16x8*>(&As[r][16 * seg + 8]) = a1;
        *reinterpret_cast<f16x8*>(&Bs[r][16 * seg])     = bh0;
        *reinterpret_cast<f16x8*>(&Bs[r][16 * seg + 8]) = bh1;
        __syncthreads();

        f16x8 af[4], bf[4];
#pragma unroll
        for (int mi = 0; mi < 4; ++mi)
            af[mi] = *reinterpret_cast<const f16x8*>(&As[wm + 16 * mi + r16][8 * qq]);
#pragma unroll
        for (int ni = 0; ni < 4; ++ni)
            bf[ni] = *reinterpret_cast<const f16x8*>(&Bs[wn + 16 * ni + r16][8 * qq]);
#pragma unroll
        for (int mi = 0; mi < 4; ++mi)
#pragma unroll
            for (int ni = 0; ni < 4; ++ni)
                acc[mi][ni] = __builtin_amdgcn_mfma_f32_16x16x32_f16(af[mi], bf[ni], acc[mi][ni], 0, 0, 0);
        __syncthreads();
    }
    // epilogue: D lane map (verified): col = lane&15, row = 4*(lane>>4)+rr
#pragma unroll
    for (int mi = 0; mi < 4; ++mi)
#pragma unroll
        for (int ni = 0; ni < 4; ++ni)
#pragma unroll
            for (int rr = 0; rr < 4; ++rr) {
                int grow = m0 + wm + 16 * mi + 4 * qq + rr;
                int gcol = n0 + wn + 16 * ni + r16;
                C[(size_t)grow * 768 + gcol] = __float2half(acc[mi][ni][rr]);
            }
}

// ---------------------------------------------------------------------------
// Persistent GRU scan. grid = 2 blocks (0 = forward, 1 = backward), 512 threads
// (8 waves). Each wave owns 6 row-tiles (96 of 768 preact rows); w_hh lives in
// VGPRs as f16 A-fragments a[6][8] (192 VGPRs). Per step:
//   issue i_all loads -> B-frags from h LDS -> 48 MFMA -> preact to LDS ->
//   barrier -> 256 gate threads (f32) -> h to LDS(next)+global -> barrier
// ---------------------------------------------------------------------------
__global__ __launch_bounds__(512, 1)
void recur_kernel(const float* __restrict__ whh_f, const float* __restrict__ whh_b,
                  const float* __restrict__ b_f,  const float* __restrict__ b_b,
                  const float* __restrict__ bn_f, const float* __restrict__ bn_b,
                  const __half* __restrict__ iall_f, const __half* __restrict__ iall_b,
                  __half* __restrict__ out /* T x 512 */) {
    const int dir = blockIdx.x;
    const float*  whh  = dir ? whh_b  : whh_f;
    const float*  bb   = dir ? b_b    : b_f;
    const float*  bn   = dir ? bn_b   : bn_f;
    const __half* iall = dir ? iall_b : iall_f;
    const int colofs   = dir ? HDIM : 0;

    const int tid = threadIdx.x;
    const int lane = tid & 63;
    const int wv = tid >> 6;      // 0..7
    const int qq = lane >> 4;     // 0..3
    const int r16 = lane & 15;

    __shared__ __align__(16) __half hbuf[2][HDIM];
    __shared__ __align__(16) float  pre[768];

    // ---- load w_hh into A-fragments (one-time) ----
    f16x8 a[6][8];
#pragma unroll
    for (int i = 0; i < 6; ++i) {
        int row = 16 * (6 * wv + i) + r16;
        const float* wr = whh + (size_t)row * HDIM + 8 * qq;
#pragma unroll
        for (int kc = 0; kc < 8; ++kc) {
            const f32x4* p4 = reinterpret_cast<const f32x4*>(wr + 32 * kc);
            f32x4 w0 = p4[0], w1 = p4[1];
            f16x8 v;
#pragma unroll
            for (int j = 0; j < 4; ++j) { v[j] = (_Float16)w0[j]; v[4 + j] = (_Float16)w1[j]; }
            a[i][kc] = v;
        }
    }
    // gate-thread constants + h init
    float cbr = 0.f, cbz = 0.f, cbg = 0.f, cbn = 0.f, hold = 0.f;
    if (tid < HDIM) {
        cbr = bb[tid]; cbz = bb[HDIM + tid]; cbg = bb[2 * HDIM + tid]; cbn = bn[tid];
        hbuf[0][tid] = __float2half(0.f);
    }
    __syncthreads();

    for (int ts = 0; ts < T_LEN; ++ts) {
        const int tp  = dir ? (T_LEN - 1 - ts) : ts;
        const int cur = ts & 1, nxt = cur ^ 1;

        // issue i_all loads early; consumed after MFMA phase (latency hidden)
        float xr = 0.f, xz = 0.f, xg = 0.f;
        if (tid < HDIM) {
            const __half* ip = iall + (size_t)tp * 768;
            xr = __half2float(ip[tid]);
            xz = __half2float(ip[HDIM + tid]);
            xg = __half2float(ip[2 * HDIM + tid]);
        }

        // B-fragments: h broadcast (4 distinct 16B lines/wave, HW broadcast)
        f16x8 bf[8];
        const __half* hb = hbuf[cur];
#pragma unroll
        for (int kc = 0; kc < 8; ++kc)
            bf[kc] = *reinterpret_cast<const f16x8*>(hb + kc * 32 + qq * 8);

        f32x4 acc[6];
#pragma unroll
        for (int i = 0; i < 6; ++i) acc[i] = (f32x4){0.f, 0.f, 0.f, 0.f};
#pragma unroll
        for (int kc = 0; kc < 8; ++kc)
#pragma unroll
            for (int i = 0; i < 6; ++i)
                acc[i] = __builtin_amdgcn_mfma_f32_16x16x32_f16(a[i][kc], bf[kc], acc[i], 0, 0, 0);

        // preacts to LDS (cols replicated -> only col-0 lanes write)
        if (r16 == 0) {
#pragma unroll
            for (int i = 0; i < 6; ++i) {
                int rowb = 16 * (6 * wv + i) + 4 * qq;
                *reinterpret_cast<f32x4*>(pre + rowb) = acc[i];
            }
        }
        __syncthreads();

        if (tid < HDIM) {
            float pr = pre[tid], pz = pre[HDIM + tid], pg = pre[2 * HDIM + tid];
            float ar = xr + cbr + pr;
            float az = xz + cbz + pz;
            float rg = 1.f / (1.f + __expf(-ar));
            float zg = 1.f / (1.f + __expf(-az));
            float ag = xg + cbg + rg * (pg + cbn);
            float e2 = __expf(-2.f * fabsf(ag));
            float th = (1.f - e2) / (1.f + e2);
            float gg = (ag >= 0.f) ? th : -th;
            float hn = (1.f - zg) * gg + zg * hold;
            hold = hn;
            __half hh = __float2half(hn);
            hbuf[nxt][tid] = hh;
            out[(size_t)tp * 512 + colofs + tid] = hh;
        }
        __syncthreads();
    }
}

// ---------------------------------------------------------------------------
// Heads: C(T x 32) = h1(T x 512) @ W'(32 x 512)^T, W' = [mu_w; sg_w; 0-pad].
// W' staged fully in LDS; 128 rows/block, 4 waves x 32 rows.
// ---------------------------------------------------------------------------
__device__ inline float softplus_f(float x) {
    return (x > 20.f) ? x : log1pf(__expf(x));
}

__global__ __launch_bounds__(256, 1)
void head_kernel(const __half* __restrict__ h1,
                 const float* __restrict__ mu_w, const float* __restrict__ mu_b,
                 const float* __restrict__ sg_w, const float* __restrict__ sg_b,
                 float* __restrict__ outp) {
    const int tid = threadIdx.x, lane = tid & 63, wv = tid >> 6;
    const int qq = lane >> 4, r16 = lane & 15;
    const int m0 = blockIdx.x * 128;

    __shared__ __align__(16) _Float16 Ws[32][520];   // +8 pad
    __shared__ __align__(16) _Float16 Hs[128][40];   // +8 pad

    {   // stage W' once
        int rw = tid >> 3, c0 = (tid & 7) * 64;
        const float* src = (rw < 10) ? (mu_w + (size_t)rw * 512 + c0)
                         : (rw < 20) ? (sg_w + (size_t)(rw - 10) * 512 + c0) : nullptr;
        for (int cc = 0; cc < 64; cc += 8) {
            f16x8 hv;
            if (src) {
                f32x4 v0 = *reinterpret_cast<const f32x4*>(src + cc);
                f32x4 v1 = *reinterpret_cast<const f32x4*>(src + cc + 4);
#pragma unroll
                for (int j = 0; j < 4; ++j) { hv[j] = (_Float16)v0[j]; hv[4 + j] = (_Float16)v1[j]; }
            } else {
#pragma unroll
                for (int j = 0; j < 8; ++j) hv[j] = (_Float16)0.f;
            }
            *reinterpret_cast<f16x8*>(&Ws[rw][c0 + cc]) = hv;
        }
    }
    __syncthreads();

    f32x4 acc[2][2];
#pragma unroll
    for (int i = 0; i < 2; ++i)
#pragma unroll
        for (int j = 0; j < 2; ++j) acc[i][j] = (f32x4){0.f, 0.f, 0.f, 0.f};

    const int r = tid >> 1, seg = tid & 1;
    for (int kc = 0; kc < 16; ++kc) {
        const f16x8* hp = reinterpret_cast<const f16x8*>(h1 + (size_t)(m0 + r) * 512 + kc * 32 + 16 * seg);
        f16x8 h0 = hp[0], h1v = hp[1];
        *reinterpret_cast<f16x8*>(&Hs[r][16 * seg])     = h0;
        *reinterpret_cast<f16x8*>(&Hs[r][16 * seg + 8]) = h1v;
        __syncthreads();
        f16x8 af[2], bf[2];
#pragma unroll
        for (int mi = 0; mi < 2; ++mi)
            af[mi] = *reinterpret_cast<const f16x8*>(&Hs[wv * 32 + 16 * mi + r16][8 * qq]);
#pragma unroll
        for (int ni = 0; ni < 2; ++ni)
            bf[ni] = *reinterpret_cast<const f16x8*>(&Ws[16 * ni + r16][kc * 32 + 8 * qq]);
#pragma unroll
        for (int mi = 0; mi < 2; ++mi)
#pragma unroll
            for (int ni = 0; ni < 2; ++ni)
                acc[mi][ni] = __builtin_amdgcn_mfma_f32_16x16x32_f16(af[mi], bf[ni], acc[mi][ni], 0, 0, 0);
        __syncthreads();
    }

#pragma unroll
    for (int mi = 0; mi < 2; ++mi)
#pragma unroll
        for (int ni = 0; ni < 2; ++ni) {
            int ch = 16 * ni + r16;
#pragma unroll
            for (int rr = 0; rr < 4; ++rr) {
                int grow = m0 + wv * 32 + 16 * mi + 4 * qq + rr;
                float v = acc[mi][ni][rr];
                if (ch < 10) {
                    outp[(size_t)grow * 10 + ch] = v + mu_b[ch];
                } else if (ch < 20) {
                    outp[(size_t)T_LEN * 10 + (size_t)grow * 10 + (ch - 10)] = softplus_f(v + sg_b[ch - 10]);
                }
            }
        }
}

// ---------------------------------------------------------------------------
extern "C" void kernel_launch(void* const* d_in, const int* in_sizes, int n_in,
                              void* d_out, int out_size, void* d_ws, size_t ws_size,
                              hipStream_t stream) {
    const float* x      = (const float*)d_in[0];
    const float* wih_f0 = (const float*)d_in[1];
    const float* whh_f0 = (const float*)d_in[2];
    const float* b_f0   = (const float*)d_in[3];
    const float* bn_f0  = (const float*)d_in[4];
    const float* wih_b0 = (const float*)d_in[5];
    const float* whh_b0 = (const float*)d_in[6];
    const float* b_b0   = (const float*)d_in[7];
    const float* bn_b0  = (const float*)d_in[8];
    const float* wih_f1 = (const float*)d_in[9];
    const float* whh_f1 = (const float*)d_in[10];
    const float* b_f1   = (const float*)d_in[11];
    const float* bn_f1  = (const float*)d_in[12];
    const float* wih_b1 = (const float*)d_in[13];
    const float* whh_b1 = (const float*)d_in[14];
    const float* b_b1   = (const float*)d_in[15];
    const float* bn_b1  = (const float*)d_in[16];
    const float* mu_w   = (const float*)d_in[17];
    const float* mu_b   = (const float*)d_in[18];
    const float* sg_w   = (const float*)d_in[19];
    const float* sg_b   = (const float*)d_in[20];

    char* ws = (char*)d_ws;
    __half* xh     = (__half*)(ws);
    __half* iall_f = (__half*)(ws + (size_t)4 * 1024 * 1024);
    __half* iall_b = (__half*)(ws + (size_t)52 * 1024 * 1024);
    __half* out0   = (__half*)(ws + (size_t)100 * 1024 * 1024);
    __half* out1   = (__half*)(ws + (size_t)132 * 1024 * 1024);

    // 1. x -> f16
    cvt_x_kernel<<<dim3((T_LEN * 64) / (256 * 8)), 256, 0, stream>>>(x, xh);
    // 2. layer-0 input projections (K=64)
    gemm_f16_kernel<<<dim3(T_LEN / 128, 6, 2), 256, 0, stream>>>(xh, wih_f0, wih_b0, iall_f, iall_b, 64);
    // 3. layer-0 scan
    recur_kernel<<<dim3(2), 512, 0, stream>>>(whh_f0, whh_b0, b_f0, b_b0, bn_f0, bn_b0, iall_f, iall_b, out0);
    // 4. layer-1 input projections (K=512)
    gemm_f16_kernel<<<dim3(T_LEN / 128, 6, 2), 256, 0, stream>>>(out0, wih_f1, wih_b1, iall_f, iall_b, 512);
    // 5. layer-1 scan
    recur_kernel<<<dim3(2), 512, 0, stream>>>(whh_f1, whh_b1, b_f1, b_b1, bn_f1, bn_b1, iall_f, iall_b, out1);
    // 6. heads
    head_kernel<<<dim3(T_LEN / 128), 256, 0, stream>>>(out1, mu_w, mu_b, sg_w, sg_b, (float*)d_out);
}